// Round 6
// baseline (1037.773 us; speedup 1.0000x reference)
//
#include <hip/hip_runtime.h>
#include <hip/hip_fp16.h>

typedef _Float16 half8 __attribute__((ext_vector_type(8)));
typedef float floatx4 __attribute__((ext_vector_type(4)));

#define GLL16(g, l)                                                            \
  __builtin_amdgcn_global_load_lds(                                            \
      (const __attribute__((address_space(1))) void*)(g),                      \
      (__attribute__((address_space(3))) void*)(l), 16, 0, 0)

#define TAU 0.25f
#define CMAX 128

__device__ inline unsigned long long score_key(float sc, int k) {
  unsigned int uu = __float_as_uint(sc);
  uu ^= (unsigned int)(((int)uu >> 31)) | 0x80000000u;  // monotone float->u32
  return ((unsigned long long)uu << 32) | (unsigned int)k;
}

// ---------------------------------------------------------------------------
// Kernel 0a: transpose x [b=16, c=512, s=2048] f32 -> xh [row=b*2048+s][c] f16
// ---------------------------------------------------------------------------
__global__ void tsplit_x(const float* __restrict__ x, _Float16* __restrict__ xh) {
  __shared__ float tile[32][33];
  const int s0 = blockIdx.x * 32;
  const int c0 = blockIdx.y * 32;
  const int b = blockIdx.z;
  const int tx = threadIdx.x, ty = threadIdx.y;
  const float* src = x + ((size_t)b * 512 + c0) * 2048 + s0;
#pragma unroll
  for (int i = ty; i < 32; i += 8) tile[i][tx] = src[(size_t)i * 2048 + tx];
  __syncthreads();
#pragma unroll
  for (int j = ty; j < 32; j += 8) {
    const int row = b * 2048 + s0 + j;
    xh[(size_t)row * 512 + c0 + tx] = (_Float16)tile[tx][j];
  }
}

// ---------------------------------------------------------------------------
// Kernel 0b: transpose centroids [c=512, n=8192] f32 -> cth [n][c] f16
// ---------------------------------------------------------------------------
__global__ void tsplit_c(const float* __restrict__ c, _Float16* __restrict__ cth) {
  __shared__ float tile[32][33];
  const int n0 = blockIdx.x * 32;
  const int c0 = blockIdx.y * 32;
  const int tx = threadIdx.x, ty = threadIdx.y;
#pragma unroll
  for (int i = ty; i < 32; i += 8) tile[i][tx] = c[(size_t)(c0 + i) * 8192 + n0 + tx];
  __syncthreads();
#pragma unroll
  for (int j = ty; j < 32; j += 8)
    cth[(size_t)(n0 + j) * 512 + c0 + tx] = (_Float16)tile[tx][j];
}

// ---------------------------------------------------------------------------
// Kernel 0c: c_sq[n] = sum_c C[c][n]^2   (fp32, exact inputs)
// ---------------------------------------------------------------------------
__global__ void csq_kernel(const float* __restrict__ c, float* __restrict__ csq) {
  __shared__ float red[256];
  const int t = threadIdx.x;
  const int nl = t & 63;
  const int cs = t >> 6;  // 0..3
  const int n = blockIdx.x * 64 + nl;
  float acc = 0.f;
  for (int cc = cs; cc < 512; cc += 4) {
    float v = c[(size_t)cc * 8192 + n];
    acc = fmaf(v, v, acc);
  }
  red[t] = acc;
  __syncthreads();
  if (t < 64) csq[n] = red[t] + red[t + 64] + red[t + 128] + red[t + 192];
}

__global__ void zero_cnts(unsigned int* c) { c[threadIdx.x] = 0u; }  // cnt, cnt2

// ---------------------------------------------------------------------------
// Kernel 1: f16 GEMM + per-(row, nblock) TOP-2.  v3 structure:
//   - A fragments loaded DIRECT global->VGPR from xh (no LDS round-trip):
//     frag = 16 contiguous bytes at row (m0+wm*64+mf*16+l15), k-chunk
//     kc*64+ks*32+lq*8 — matches the verified A layout m=l&15, k=lq*8+j.
//   - B staged via global_load_lds, DOUBLE-buffered 16 KiB x2 -> one barrier
//     per kc, drain covers only 4 GLLs; B prefetch in flight across compute.
//   - LDS pipe traffic per block-kc: 96 KiB -> 48 KiB; barriers 16 -> 8.
// ---------------------------------------------------------------------------
__launch_bounds__(256, 4)
__global__ void gemm_top2(const _Float16* __restrict__ xh, const _Float16* __restrict__ cth,
                          const float* __restrict__ csq, float* __restrict__ pv1,
                          int* __restrict__ pi1, float* __restrict__ pv2,
                          int* __restrict__ pi2) {
  __shared__ __align__(16) unsigned char smem[32768];  // B double buffer, 16 KiB each
  __shared__ float ep_v1[128][2], ep_v2[128][2];
  __shared__ int ep_i1[128][2], ep_i2[128][2];

  const int t = threadIdx.x;
  const int m0 = blockIdx.x * 128;
  const int n0 = blockIdx.y * 128;

  // B staging: 1024 16B-chunks per kc (chunk = kq*128 + col); thread t owns
  // chunks {t, t+256, t+512, t+768}.
  const _Float16* gB[4];
#pragma unroll
  for (int p = 0; p < 4; ++p) {
    const int ch = p * 256 + t;
    const int col = ch & 127, kq = ch >> 7;
    gB[p] = cth + (size_t)(n0 + col) * 512 + kq * 8;
  }

  const int l = t & 63;
  const int w = t >> 6;
  const int wm = w >> 1, wn = w & 1;
  const int l15 = l & 15, lq = l >> 4;

  // A direct: per-mf row pointer; half8 index = kc*8 + ks*4 + lq
  const half8* gA[4];
#pragma unroll
  for (int mf = 0; mf < 4; ++mf)
    gA[mf] = (const half8*)(xh + (size_t)(m0 + wm * 64 + mf * 16 + l15) * 512);

  const int bBase = wn * 64 + l15;  // + nf*16; chunk idx in buffer is kq*128 + this

  floatx4 acc[4][4] = {};

  auto stageB = [&](int buf, int kc) {
#pragma unroll
    for (int p = 0; p < 4; ++p)
      GLL16(gB[p] + kc * 64, smem + buf * 16384 + (p * 256 + t) * 16);
  };

  stageB(0, 0);
  int buf = 0;
  for (int kc = 0; kc < 8; ++kc) {
    __syncthreads();  // drains stage(kc)'s GLLs; guards prev compute's ds_reads
    if (kc < 7) stageB(buf ^ 1, kc + 1);
    const half8* SB = (const half8*)(smem + buf * 16384);
#pragma unroll
    for (int ks = 0; ks < 2; ++ks) {
      const int kq = ks * 4 + lq;  // 0..7
      half8 a[4], b[4];
#pragma unroll
      for (int f = 0; f < 4; ++f) {
        a[f] = gA[f][kc * 8 + kq];
        b[f] = SB[kq * 128 + bBase + f * 16];
      }
#pragma unroll
      for (int mf = 0; mf < 4; ++mf)
#pragma unroll
        for (int nf = 0; nf < 4; ++nf)
          acc[mf][nf] = __builtin_amdgcn_mfma_f32_16x16x32_f16(a[mf], b[nf], acc[mf][nf], 0, 0, 0);
    }
    buf ^= 1;
  }

  // epilogue: top-2 (value,index) over this block's 128 columns
  float cs[4];
#pragma unroll
  for (int nf = 0; nf < 4; ++nf) cs[nf] = csq[n0 + wn * 64 + nf * 16 + l15];

#pragma unroll
  for (int mf = 0; mf < 4; ++mf) {
#pragma unroll
    for (int reg = 0; reg < 4; ++reg) {
      float v1 = INFINITY, v2 = INFINITY;
      int i1 = 0, i2 = 0;
#pragma unroll
      for (int nf = 0; nf < 4; ++nf) {
        float sv = fmaf(-2.f, acc[mf][nf][reg], cs[nf]);
        int si = n0 + wn * 64 + nf * 16 + l15;
        if (sv < v1) { v2 = v1; i2 = i1; v1 = sv; i1 = si; }
        else if (sv < v2) { v2 = sv; i2 = si; }
      }
#pragma unroll
      for (int off = 8; off >= 1; off >>= 1) {
        float w1 = __shfl_xor(v1, off, 64);
        int j1 = __shfl_xor(i1, off, 64);
        float w2 = __shfl_xor(v2, off, 64);
        int j2 = __shfl_xor(i2, off, 64);
        if (w1 < v1 || (w1 == v1 && j1 < i1)) {
          if (w2 < v1 || (w2 == v1 && j2 < i1)) { v2 = w2; i2 = j2; }
          else { v2 = v1; i2 = i1; }
          v1 = w1; i1 = j1;
        } else {
          if (w1 < v2 || (w1 == v2 && j1 < i2)) { v2 = w1; i2 = j1; }
        }
      }
      if (l15 == 0) {
        int rl = wm * 64 + mf * 16 + lq * 4 + reg;
        ep_v1[rl][wn] = v1;
        ep_i1[rl][wn] = i1;
        ep_v2[rl][wn] = v2;
        ep_i2[rl][wn] = i2;
      }
    }
  }
  __syncthreads();
  if (t < 128) {
    float v1 = ep_v1[t][0], v2 = ep_v2[t][0];
    int i1 = ep_i1[t][0], i2 = ep_i2[t][0];
    float w1 = ep_v1[t][1], w2 = ep_v2[t][1];
    int j1 = ep_i1[t][1], j2 = ep_i2[t][1];
    if (w1 < v1 || (w1 == v1 && j1 < i1)) {
      if (w2 < v1 || (w2 == v1 && j2 < i1)) { v2 = w2; i2 = j2; }
      else { v2 = v1; i2 = i1; }
      v1 = w1; i1 = j1;
    } else {
      if (w1 < v2 || (w1 == v2 && j1 < i2)) { v2 = w1; i2 = j1; }
    }
    const size_t o = (size_t)blockIdx.y * 32768 + m0 + t;
    pv1[o] = v1;
    pi1[o] = i1;
    pv2[o] = v2;
    pi2[o] = i2;
  }
}

// ---------------------------------------------------------------------------
// Kernel 2: merge 64 nblock top-2s; write labels + rowbest; flag small margins.
// ---------------------------------------------------------------------------
__global__ void final_top2(const float* __restrict__ pv1, const int* __restrict__ pi1,
                           const float* __restrict__ pv2, int* __restrict__ out,
                           float* __restrict__ rowbest, unsigned int* __restrict__ cnt,
                           int* __restrict__ list) {
  const int row = blockIdx.x * 256 + threadIdx.x;
  float v1 = INFINITY, v2 = INFINITY;
  int i1 = 0;
  for (int nb = 0; nb < 64; ++nb) {
    const size_t o = (size_t)nb * 32768 + row;
    float w1 = pv1[o], w2 = pv2[o];
    int j1 = pi1[o];
    if (w1 < v1 || (w1 == v1 && j1 < i1)) {
      v2 = fminf(v1, w2);
      v1 = w1; i1 = j1;
    } else {
      v2 = fminf(v2, w1);
    }
  }
  out[row] = i1;
  rowbest[row] = v1;
  if (v2 - v1 < TAU) {
    unsigned int pos = atomicAdd(cnt, 1u);
    list[pos] = row;
  }
}

// ---------------------------------------------------------------------------
// Kernel 3: candidate-set exact rescore for flagged rows.
// ---------------------------------------------------------------------------
__global__ void cand_refine(const float* __restrict__ x, const float* __restrict__ cen,
                            const float* __restrict__ csq, const float* __restrict__ pv1,
                            const int* __restrict__ pi1, const float* __restrict__ pv2,
                            const int* __restrict__ pi2, const float* __restrict__ rowbest,
                            const unsigned int* __restrict__ cnt, const int* __restrict__ list,
                            unsigned int* __restrict__ cnt2, int* __restrict__ list2,
                            unsigned long long* __restrict__ slots, int* __restrict__ out) {
  __shared__ float xs[512];
  __shared__ int cand[CMAX];
  __shared__ int ccnt_s, needfull_s;
  __shared__ unsigned long long wbest[4];
  const int t = threadIdx.x;
  const int lane = t & 63, wid = t >> 6;
  const int n = (int)*cnt;
  for (int u = blockIdx.x; u < n; u += gridDim.x) {
    __syncthreads();  // protect previous iteration's xs/cand readers
    const int row = list[u];
    const int b = row >> 11, s = row & 2047;
    if (t == 0) { ccnt_s = 0; needfull_s = 0; }
    __syncthreads();
    xs[t] = x[((size_t)(b * 512 + t)) * 2048 + s];
    xs[t + 256] = x[((size_t)(b * 512 + t + 256)) * 2048 + s];
    const float thr = rowbest[row] + TAU;
    if (t < 64) {
      const size_t o = (size_t)t * 32768 + row;
      float w1 = pv1[o];
      if (w1 < thr) {
        int p = atomicAdd(&ccnt_s, 1);
        if (p < CMAX) cand[p] = pi1[o];
        float w2 = pv2[o];
        if (w2 < thr) {
          int q = atomicAdd(&ccnt_s, 1);
          if (q < CMAX) cand[q] = pi2[o];
          needfull_s = 1;  // 3rd-best in this nblock unknown
        }
      }
    }
    __syncthreads();
    int ccnt = ccnt_s < CMAX ? ccnt_s : CMAX;
    unsigned long long best = ~0ULL;
    for (int ci = wid; ci < ccnt; ci += 4) {
      const int k = cand[ci];
      float p0 = 0.f, p1 = 0.f;
#pragma unroll
      for (int j = 0; j < 4; ++j)
        p0 = fmaf(xs[lane + 64 * j], cen[(size_t)(lane + 64 * j) * 8192 + k], p0);
#pragma unroll
      for (int j = 4; j < 8; ++j)
        p1 = fmaf(xs[lane + 64 * j], cen[(size_t)(lane + 64 * j) * 8192 + k], p1);
      float d = p0 + p1;
#pragma unroll
      for (int off = 32; off >= 1; off >>= 1) d += __shfl_xor(d, off, 64);
      unsigned long long key = score_key(fmaf(-2.f, d, csq[k]), k);
      if (key < best) best = key;
    }
    if (lane == 0) wbest[wid] = best;
    __syncthreads();
    if (t == 0) {
      unsigned long long m = wbest[0];
#pragma unroll
      for (int w2 = 1; w2 < 4; ++w2)
        if (wbest[w2] < m) m = wbest[w2];
      out[row] = (int)(unsigned int)(m & 0xFFFFFFFFULL);
      if (needfull_s) {
        slots[row] = ~0ULL;
        unsigned int pos = atomicAdd(cnt2, 1u);
        list2[pos] = row;
      }
    }
  }
}

// ---------------------------------------------------------------------------
// Kernel 4: full 8192-scan for the rare rows needing it.
// ---------------------------------------------------------------------------
__global__ void fullscan(const float* __restrict__ x, const float* __restrict__ cen,
                         const float* __restrict__ csq, const unsigned int* __restrict__ cnt2,
                         const int* __restrict__ list2, unsigned long long* __restrict__ slots) {
  __shared__ float xs[512];
  __shared__ unsigned long long red[256];
  const int t = threadIdx.x;
  const int n2 = (int)*cnt2;
  const int units = n2 * 16;
  for (int u = blockIdx.x; u < units; u += gridDim.x) {
    __syncthreads();
    const int row = list2[u >> 4];
    const int sl = u & 15;
    const int b = row >> 11, s = row & 2047;
    xs[t] = x[((size_t)(b * 512 + t)) * 2048 + s];
    xs[t + 256] = x[((size_t)(b * 512 + t + 256)) * 2048 + s];
    __syncthreads();
    const int k0 = sl * 512 + t;
    float tot0 = 0.f, tot1 = 0.f;
#pragma unroll
    for (int ch = 0; ch < 4; ++ch) {
      float a0 = 0.f, a1 = 0.f;
      for (int c = ch * 128; c < ch * 128 + 128; ++c) {
        float xv = xs[c];
        a0 = fmaf(xv, cen[(size_t)c * 8192 + k0], a0);
        a1 = fmaf(xv, cen[(size_t)c * 8192 + k0 + 256], a1);
      }
      tot0 += a0;
      tot1 += a1;
    }
    unsigned long long k1 = score_key(fmaf(-2.f, tot0, csq[k0]), k0);
    unsigned long long k2 = score_key(fmaf(-2.f, tot1, csq[k0 + 256]), k0 + 256);
    red[t] = k1 < k2 ? k1 : k2;
    __syncthreads();
    for (int off = 128; off >= 1; off >>= 1) {
      if (t < off && red[t + off] < red[t]) red[t] = red[t + off];
      __syncthreads();
    }
    if (t == 0) atomicMin(&slots[row], red[0]);
  }
}

// ---------------------------------------------------------------------------
// Kernel 5: fold fullscan results into labels.
// ---------------------------------------------------------------------------
__global__ void fixup2(const unsigned int* __restrict__ cnt2, const int* __restrict__ list2,
                       const unsigned long long* __restrict__ slots, int* __restrict__ out) {
  const int n2 = (int)*cnt2;
  for (int i = blockIdx.x * blockDim.x + threadIdx.x; i < n2; i += blockDim.x * gridDim.x) {
    const int row = list2[i];
    out[row] = (int)(unsigned int)(slots[row] & 0xFFFFFFFFULL);
  }
}

// ---------------------------------------------------------------------------
// Fallback (only if ws too small): exact distances, slow but correct.
// ---------------------------------------------------------------------------
__global__ void fallback_kernel(const float* __restrict__ x, const float* __restrict__ cen,
                                int* __restrict__ out) {
  __shared__ float xrow[512];
  __shared__ float rv[256];
  __shared__ int ri[256];
  const int row = blockIdx.x;
  const int b = row >> 11, s = row & 2047;
  const int t = threadIdx.x;
  for (int c = t; c < 512; c += 256) xrow[c] = x[((size_t)b * 512 + c) * 2048 + s];
  __syncthreads();
  float bv = INFINITY;
  int bi = 0;
  for (int k = t; k < 8192; k += 256) {
    float d = 0.f;
    for (int c = 0; c < 512; ++c) {
      float diff = xrow[c] - cen[(size_t)c * 8192 + k];
      d = fmaf(diff, diff, d);
    }
    if (d < bv) { bv = d; bi = k; }
  }
  rv[t] = bv;
  ri[t] = bi;
  __syncthreads();
  for (int off = 128; off > 0; off >>= 1) {
    if (t < off) {
      if (rv[t + off] < rv[t] || (rv[t + off] == rv[t] && ri[t + off] < ri[t])) {
        rv[t] = rv[t + off];
        ri[t] = ri[t + off];
      }
    }
    __syncthreads();
  }
  if (t == 0) out[row] = ri[0];
}

// ---------------------------------------------------------------------------
extern "C" void kernel_launch(void* const* d_in, const int* in_sizes, int n_in,
                              void* d_out, int out_size, void* d_ws, size_t ws_size,
                              hipStream_t stream) {
  const float* x = (const float*)d_in[0];    // [16, 512, 2048]
  const float* cen = (const float*)d_in[1];  // [512, 8192]
  int* out = (int*)d_out;                    // [32768] int32 labels

  const size_t XSZ = (size_t)32768 * 512;  // halfs
  const size_t CSZ = (size_t)8192 * 512;   // halfs
  const size_t OFF_CTH = XSZ * 2;
  const size_t OFF_CSQ = OFF_CTH + CSZ * 2;
  const size_t OFF_PV1 = OFF_CSQ + 8192 * 4;
  const size_t OFF_PV2 = OFF_PV1 + (size_t)64 * 32768 * 4;
  const size_t OFF_PI1 = OFF_PV2 + (size_t)64 * 32768 * 4;
  const size_t OFF_PI2 = OFF_PI1 + (size_t)64 * 32768 * 4;
  const size_t OFF_RB = OFF_PI2 + (size_t)64 * 32768 * 4;
  const size_t OFF_SLOT = OFF_RB + (size_t)32768 * 4;
  const size_t OFF_LIST = OFF_SLOT + (size_t)32768 * 8;
  const size_t OFF_LIST2 = OFF_LIST + (size_t)32768 * 4;
  const size_t OFF_CNT = OFF_LIST2 + (size_t)32768 * 4;
  const size_t NEED = OFF_CNT + 16;

  if (ws_size < NEED) {
    fallback_kernel<<<32768, 256, 0, stream>>>(x, cen, out);
    return;
  }

  char* ws = (char*)d_ws;
  _Float16* xh = (_Float16*)ws;
  _Float16* cth = (_Float16*)(ws + OFF_CTH);
  float* csq = (float*)(ws + OFF_CSQ);
  float* pv1 = (float*)(ws + OFF_PV1);
  float* pv2 = (float*)(ws + OFF_PV2);
  int* pi1 = (int*)(ws + OFF_PI1);
  int* pi2 = (int*)(ws + OFF_PI2);
  float* rowbest = (float*)(ws + OFF_RB);
  unsigned long long* slots = (unsigned long long*)(ws + OFF_SLOT);
  int* list = (int*)(ws + OFF_LIST);
  int* list2 = (int*)(ws + OFF_LIST2);
  unsigned int* cnts = (unsigned int*)(ws + OFF_CNT);  // [0]=cnt, [1]=cnt2

  tsplit_x<<<dim3(64, 16, 16), dim3(32, 8), 0, stream>>>(x, xh);
  tsplit_c<<<dim3(256, 16), dim3(32, 8), 0, stream>>>(cen, cth);
  csq_kernel<<<128, 256, 0, stream>>>(cen, csq);
  zero_cnts<<<1, 2, 0, stream>>>(cnts);
  gemm_top2<<<dim3(256, 64), 256, 0, stream>>>(xh, cth, csq, pv1, pi1, pv2, pi2);
  final_top2<<<128, 256, 0, stream>>>(pv1, pi1, pv2, out, rowbest, cnts, list);
  cand_refine<<<512, 256, 0, stream>>>(x, cen, csq, pv1, pi1, pv2, pi2, rowbest,
                                       cnts, list, cnts + 1, list2, slots, out);
  fullscan<<<256, 256, 0, stream>>>(x, cen, csq, cnts + 1, list2, slots);
  fixup2<<<4, 256, 0, stream>>>(cnts + 1, list2, slots, out);
}

// Round 7
// 835.076 us; speedup vs baseline: 1.2427x; 1.2427x over previous
//
#include <hip/hip_runtime.h>
#include <hip/hip_fp16.h>

typedef _Float16 half8 __attribute__((ext_vector_type(8)));
typedef float floatx4 __attribute__((ext_vector_type(4)));

#define GLL16(g, l)                                                            \
  __builtin_amdgcn_global_load_lds(                                            \
      (const __attribute__((address_space(1))) void*)(g),                      \
      (__attribute__((address_space(3))) void*)(l), 16, 0, 0)

#define TAU 0.25f
#define CMAX 128

__device__ inline unsigned map_score(float f) {
  unsigned u = __float_as_uint(f);
  return u ^ ((unsigned)(((int)u) >> 31) | 0x80000000u);  // monotone float->u32
}
__device__ inline float unmap_score(unsigned m) {
  unsigned u = (m & 0x80000000u) ? (m ^ 0x80000000u) : ~m;
  return __uint_as_float(u);
}
__device__ inline unsigned long long score_key(float sc, int k) {
  return ((unsigned long long)map_score(sc) << 32) | (unsigned int)k;
}

// ---------------------------------------------------------------------------
// Kernel 0a: transpose x [b=16, c=512, s=2048] f32 -> xh [row=b*2048+s][c] f16
// ---------------------------------------------------------------------------
__global__ void tsplit_x(const float* __restrict__ x, _Float16* __restrict__ xh) {
  __shared__ float tile[32][33];
  const int s0 = blockIdx.x * 32;
  const int c0 = blockIdx.y * 32;
  const int b = blockIdx.z;
  const int tx = threadIdx.x, ty = threadIdx.y;
  const float* src = x + ((size_t)b * 512 + c0) * 2048 + s0;
#pragma unroll
  for (int i = ty; i < 32; i += 8) tile[i][tx] = src[(size_t)i * 2048 + tx];
  __syncthreads();
#pragma unroll
  for (int j = ty; j < 32; j += 8) {
    const int row = b * 2048 + s0 + j;
    xh[(size_t)row * 512 + c0 + tx] = (_Float16)tile[tx][j];
  }
}

// ---------------------------------------------------------------------------
// Kernel 0b: transpose centroids [c=512, n=8192] f32 -> cth [n][c] f16
// ---------------------------------------------------------------------------
__global__ void tsplit_c(const float* __restrict__ c, _Float16* __restrict__ cth) {
  __shared__ float tile[32][33];
  const int n0 = blockIdx.x * 32;
  const int c0 = blockIdx.y * 32;
  const int tx = threadIdx.x, ty = threadIdx.y;
#pragma unroll
  for (int i = ty; i < 32; i += 8) tile[i][tx] = c[(size_t)(c0 + i) * 8192 + n0 + tx];
  __syncthreads();
#pragma unroll
  for (int j = ty; j < 32; j += 8)
    cth[(size_t)(n0 + j) * 512 + c0 + tx] = (_Float16)tile[tx][j];
}

// ---------------------------------------------------------------------------
// Kernel 0c: c_sq[n] = sum_c C[c][n]^2   (fp32, exact inputs)
// ---------------------------------------------------------------------------
__global__ void csq_kernel(const float* __restrict__ c, float* __restrict__ csq) {
  __shared__ float red[256];
  const int t = threadIdx.x;
  const int nl = t & 63;
  const int cs = t >> 6;  // 0..3
  const int n = blockIdx.x * 64 + nl;
  float acc = 0.f;
  for (int cc = cs; cc < 512; cc += 4) {
    float v = c[(size_t)cc * 8192 + n];
    acc = fmaf(v, v, acc);
  }
  red[t] = acc;
  __syncthreads();
  if (t < 64) csq[n] = red[t] + red[t + 64] + red[t + 128] + red[t + 192];
}

__global__ void zero_cnts(unsigned int* c) { c[threadIdx.x] = 0u; }  // cnt, cnt2

// ---------------------------------------------------------------------------
// Kernel 1: f16 GEMM + per-(row, nblock) TOP-2.  Round-5 K-loop (proven 660us)
//   + DPP epilogue:
//   - A and B both staged via global_load_lds, single 32 KiB buffer, BK=64.
//   - epilogue 16-lane reduction via DPP row_ror (VALU pipe) instead of
//     __shfl_xor (LDS pipe) — the LDS pipe was the serialized resource.
//   - partials: k1 = (mapped_score<<32)|idx (u64), v2 = mapped score (u32).
//     No i2: needfull-fullscan already covers hidden same-nblock 3rds.
// ---------------------------------------------------------------------------
__launch_bounds__(256, 4)
__global__ void gemm_top2(const _Float16* __restrict__ xh, const _Float16* __restrict__ cth,
                          const float* __restrict__ csq,
                          unsigned long long* __restrict__ pk1,
                          unsigned int* __restrict__ pv2) {
  __shared__ __align__(16) unsigned char smem[32768];
  __shared__ unsigned long long ep_k1[128][2];
  __shared__ unsigned int ep_v2[128][2];

  const int t = threadIdx.x;
  const int m0 = blockIdx.x * 128;
  const int n0 = blockIdx.y * 128;

  // staging: 1024 16B-chunks per operand per kc (chunk = kq*128 + row)
  const _Float16* gA[4];
  const _Float16* gB[4];
#pragma unroll
  for (int p = 0; p < 4; ++p) {
    const int ch = p * 256 + t;
    const int row = ch & 127, kq = ch >> 7;
    gA[p] = xh + (size_t)(m0 + row) * 512 + kq * 8;
    gB[p] = cth + (size_t)(n0 + row) * 512 + kq * 8;
  }

  const int l = t & 63;
  const int w = t >> 6;
  const int wm = w >> 1, wn = w & 1;
  const int l15 = l & 15, lq = l >> 4;
  const int aBase = wm * 64 + l15;
  const int bBase = 1024 + wn * 64 + l15;

  floatx4 acc[4][4] = {};
  const half8* S = (const half8*)smem;

  for (int kc = 0; kc < 8; ++kc) {
    const int k0 = kc * 64;
#pragma unroll
    for (int p = 0; p < 4; ++p) {
      GLL16(gA[p] + k0, smem + (p * 256 + t) * 16);
      GLL16(gB[p] + k0, smem + 16384 + (p * 256 + t) * 16);
    }
    __syncthreads();
#pragma unroll
    for (int ks = 0; ks < 2; ++ks) {
      const int ko = (ks * 4 + lq) * 128;
      half8 a[4], b[4];
#pragma unroll
      for (int f = 0; f < 4; ++f) {
        a[f] = S[ko + aBase + f * 16];
        b[f] = S[ko + bBase + f * 16];
      }
#pragma unroll
      for (int mf = 0; mf < 4; ++mf)
#pragma unroll
        for (int nf = 0; nf < 4; ++nf)
          acc[mf][nf] = __builtin_amdgcn_mfma_f32_16x16x32_f16(a[mf], b[nf], acc[mf][nf], 0, 0, 0);
    }
    __syncthreads();
  }

  // ---- epilogue: top-2 over this block's 128 cols, DPP row_ror reduction
  float cs[4];
#pragma unroll
  for (int nf = 0; nf < 4; ++nf) cs[nf] = csq[n0 + wn * 64 + nf * 16 + l15];

#define ROR_STEP(CTRL)                                                                       \
  {                                                                                          \
    unsigned ohi = (unsigned)__builtin_amdgcn_update_dpp(0, (int)hi, (CTRL), 0xF, 0xF, true); \
    unsigned olo = (unsigned)__builtin_amdgcn_update_dpp(0, (int)lo, (CTRL), 0xF, 0xF, true); \
    unsigned ov2 = (unsigned)__builtin_amdgcn_update_dpp(0, (int)v2m, (CTRL), 0xF, 0xF, true); \
    unsigned long long ok = ((unsigned long long)ohi << 32) | olo;                           \
    unsigned long long ck = ((unsigned long long)hi << 32) | lo;                             \
    unsigned wsc = (ck < ok) ? ohi : hi;                                                     \
    if (ok < ck) { hi = ohi; lo = olo; }                                                     \
    v2m = v2m < ov2 ? v2m : ov2;                                                             \
    v2m = v2m < wsc ? v2m : wsc;                                                             \
  }

#pragma unroll
  for (int mf = 0; mf < 4; ++mf) {
#pragma unroll
    for (int reg = 0; reg < 4; ++reg) {
      unsigned long long k1;
      unsigned v2m = 0xFFFFFFFFu;
      {
        float sv = fmaf(-2.f, acc[mf][0][reg], cs[0]);
        k1 = score_key(sv, n0 + wn * 64 + l15);
      }
#pragma unroll
      for (int nf = 1; nf < 4; ++nf) {
        float sv = fmaf(-2.f, acc[mf][nf][reg], cs[nf]);
        unsigned long long key = score_key(sv, n0 + wn * 64 + nf * 16 + l15);
        if (key < k1) {
          v2m = v2m < (unsigned)(k1 >> 32) ? v2m : (unsigned)(k1 >> 32);
          k1 = key;
        } else {
          v2m = v2m < (unsigned)(key >> 32) ? v2m : (unsigned)(key >> 32);
        }
      }
      unsigned hi = (unsigned)(k1 >> 32), lo = (unsigned)k1;
      ROR_STEP(0x121)  // row_ror:1
      ROR_STEP(0x122)  // row_ror:2
      ROR_STEP(0x124)  // row_ror:4
      ROR_STEP(0x128)  // row_ror:8
      if (l15 == 0) {
        int rl = wm * 64 + mf * 16 + lq * 4 + reg;
        ep_k1[rl][wn] = ((unsigned long long)hi << 32) | lo;
        ep_v2[rl][wn] = v2m;
      }
    }
  }
#undef ROR_STEP
  __syncthreads();
  if (t < 128) {
    unsigned long long ka = ep_k1[t][0], kb = ep_k1[t][1];
    unsigned v2 = ep_v2[t][0] < ep_v2[t][1] ? ep_v2[t][0] : ep_v2[t][1];
    unsigned wsc = (ka < kb) ? (unsigned)(kb >> 32) : (unsigned)(ka >> 32);
    unsigned long long k = ka < kb ? ka : kb;
    v2 = v2 < wsc ? v2 : wsc;
    const size_t o = (size_t)blockIdx.y * 32768 + m0 + t;
    pk1[o] = k;
    pv2[o] = v2;
  }
}

// ---------------------------------------------------------------------------
// Kernel 2: merge 64 nblock top-2s; write labels + rowbest; flag small margins.
// ---------------------------------------------------------------------------
__global__ void final_top2(const unsigned long long* __restrict__ pk1,
                           const unsigned int* __restrict__ pv2, int* __restrict__ out,
                           unsigned int* __restrict__ rowbest_m, unsigned int* __restrict__ cnt,
                           int* __restrict__ list) {
  const int row = blockIdx.x * 256 + threadIdx.x;
  unsigned long long K = ~0ULL;
  unsigned V2 = 0xFFFFFFFFu;
  for (int nb = 0; nb < 64; ++nb) {
    const size_t o = (size_t)nb * 32768 + row;
    unsigned long long k = pk1[o];
    unsigned v2 = pv2[o];
    unsigned wsc = (K < k) ? (unsigned)(k >> 32) : (unsigned)(K >> 32);
    if (k < K) K = k;
    V2 = V2 < v2 ? V2 : v2;
    V2 = V2 < wsc ? V2 : wsc;
  }
  out[row] = (int)(unsigned)(K & 0xFFFFFFFFULL);
  rowbest_m[row] = (unsigned)(K >> 32);
  if (unmap_score(V2) - unmap_score((unsigned)(K >> 32)) < TAU) {
    unsigned int pos = atomicAdd(cnt, 1u);
    list[pos] = row;
  }
}

// ---------------------------------------------------------------------------
// Kernel 3: candidate-set exact rescore for flagged rows.
//   Candidates = per-nblock best entries with approx score < v1g + TAU.
//   Any nblock with v2 < thr -> hidden 3rd possible -> full scan for row.
// ---------------------------------------------------------------------------
__global__ void cand_refine(const float* __restrict__ x, const float* __restrict__ cen,
                            const float* __restrict__ csq,
                            const unsigned long long* __restrict__ pk1,
                            const unsigned int* __restrict__ pv2,
                            const unsigned int* __restrict__ rowbest_m,
                            const unsigned int* __restrict__ cnt, const int* __restrict__ list,
                            unsigned int* __restrict__ cnt2, int* __restrict__ list2,
                            unsigned long long* __restrict__ slots, int* __restrict__ out) {
  __shared__ float xs[512];
  __shared__ int cand[CMAX];
  __shared__ int ccnt_s, needfull_s;
  __shared__ unsigned long long wbest[4];
  const int t = threadIdx.x;
  const int lane = t & 63, wid = t >> 6;
  const int n = (int)*cnt;
  for (int u = blockIdx.x; u < n; u += gridDim.x) {
    __syncthreads();  // protect previous iteration's xs/cand readers
    const int row = list[u];
    const int b = row >> 11, s = row & 2047;
    if (t == 0) { ccnt_s = 0; needfull_s = 0; }
    __syncthreads();
    xs[t] = x[((size_t)(b * 512 + t)) * 2048 + s];
    xs[t + 256] = x[((size_t)(b * 512 + t + 256)) * 2048 + s];
    const unsigned thr_m = map_score(unmap_score(rowbest_m[row]) + TAU);
    if (t < 64) {
      const size_t o = (size_t)t * 32768 + row;
      unsigned long long k1 = pk1[o];
      if ((unsigned)(k1 >> 32) < thr_m) {
        int p = atomicAdd(&ccnt_s, 1);
        if (p < CMAX) cand[p] = (int)(unsigned)(k1 & 0xFFFFFFFFULL);
        if (pv2[o] < thr_m) needfull_s = 1;
      }
    }
    __syncthreads();
    int ccnt = ccnt_s < CMAX ? ccnt_s : CMAX;
    unsigned long long best = ~0ULL;
    for (int ci = wid; ci < ccnt; ci += 4) {
      const int k = cand[ci];
      float p0 = 0.f, p1 = 0.f;
#pragma unroll
      for (int j = 0; j < 4; ++j)
        p0 = fmaf(xs[lane + 64 * j], cen[(size_t)(lane + 64 * j) * 8192 + k], p0);
#pragma unroll
      for (int j = 4; j < 8; ++j)
        p1 = fmaf(xs[lane + 64 * j], cen[(size_t)(lane + 64 * j) * 8192 + k], p1);
      float d = p0 + p1;
#pragma unroll
      for (int off = 32; off >= 1; off >>= 1) d += __shfl_xor(d, off, 64);
      unsigned long long key = score_key(fmaf(-2.f, d, csq[k]), k);
      if (key < best) best = key;
    }
    if (lane == 0) wbest[wid] = best;
    __syncthreads();
    if (t == 0) {
      unsigned long long m = wbest[0];
#pragma unroll
      for (int w2 = 1; w2 < 4; ++w2)
        if (wbest[w2] < m) m = wbest[w2];
      out[row] = (int)(unsigned)(m & 0xFFFFFFFFULL);
      if (needfull_s) {
        slots[row] = ~0ULL;
        unsigned int pos = atomicAdd(cnt2, 1u);
        list2[pos] = row;
      }
    }
  }
}

// ---------------------------------------------------------------------------
// Kernel 4: full 8192-scan for the rare rows needing it.
// ---------------------------------------------------------------------------
__global__ void fullscan(const float* __restrict__ x, const float* __restrict__ cen,
                         const float* __restrict__ csq, const unsigned int* __restrict__ cnt2,
                         const int* __restrict__ list2, unsigned long long* __restrict__ slots) {
  __shared__ float xs[512];
  __shared__ unsigned long long red[256];
  const int t = threadIdx.x;
  const int n2 = (int)*cnt2;
  const int units = n2 * 16;
  for (int u = blockIdx.x; u < units; u += gridDim.x) {
    __syncthreads();
    const int row = list2[u >> 4];
    const int sl = u & 15;
    const int b = row >> 11, s = row & 2047;
    xs[t] = x[((size_t)(b * 512 + t)) * 2048 + s];
    xs[t + 256] = x[((size_t)(b * 512 + t + 256)) * 2048 + s];
    __syncthreads();
    const int k0 = sl * 512 + t;
    float tot0 = 0.f, tot1 = 0.f;
#pragma unroll
    for (int ch = 0; ch < 4; ++ch) {
      float a0 = 0.f, a1 = 0.f;
      for (int c = ch * 128; c < ch * 128 + 128; ++c) {
        float xv = xs[c];
        a0 = fmaf(xv, cen[(size_t)c * 8192 + k0], a0);
        a1 = fmaf(xv, cen[(size_t)c * 8192 + k0 + 256], a1);
      }
      tot0 += a0;
      tot1 += a1;
    }
    unsigned long long k1 = score_key(fmaf(-2.f, tot0, csq[k0]), k0);
    unsigned long long k2 = score_key(fmaf(-2.f, tot1, csq[k0 + 256]), k0 + 256);
    red[t] = k1 < k2 ? k1 : k2;
    __syncthreads();
    for (int off = 128; off >= 1; off >>= 1) {
      if (t < off && red[t + off] < red[t]) red[t] = red[t + off];
      __syncthreads();
    }
    if (t == 0) atomicMin(&slots[row], red[0]);
  }
}

// ---------------------------------------------------------------------------
// Kernel 5: fold fullscan results into labels.
// ---------------------------------------------------------------------------
__global__ void fixup2(const unsigned int* __restrict__ cnt2, const int* __restrict__ list2,
                       const unsigned long long* __restrict__ slots, int* __restrict__ out) {
  const int n2 = (int)*cnt2;
  for (int i = blockIdx.x * blockDim.x + threadIdx.x; i < n2; i += blockDim.x * gridDim.x) {
    const int row = list2[i];
    out[row] = (int)(unsigned)(slots[row] & 0xFFFFFFFFULL);
  }
}

// ---------------------------------------------------------------------------
// Fallback (only if ws too small): exact distances, slow but correct.
// ---------------------------------------------------------------------------
__global__ void fallback_kernel(const float* __restrict__ x, const float* __restrict__ cen,
                                int* __restrict__ out) {
  __shared__ float xrow[512];
  __shared__ float rv[256];
  __shared__ int ri[256];
  const int row = blockIdx.x;
  const int b = row >> 11, s = row & 2047;
  const int t = threadIdx.x;
  for (int c = t; c < 512; c += 256) xrow[c] = x[((size_t)b * 512 + c) * 2048 + s];
  __syncthreads();
  float bv = INFINITY;
  int bi = 0;
  for (int k = t; k < 8192; k += 256) {
    float d = 0.f;
    for (int c = 0; c < 512; ++c) {
      float diff = xrow[c] - cen[(size_t)c * 8192 + k];
      d = fmaf(diff, diff, d);
    }
    if (d < bv) { bv = d; bi = k; }
  }
  rv[t] = bv;
  ri[t] = bi;
  __syncthreads();
  for (int off = 128; off > 0; off >>= 1) {
    if (t < off) {
      if (rv[t + off] < rv[t] || (rv[t + off] == rv[t] && ri[t + off] < ri[t])) {
        rv[t] = rv[t + off];
        ri[t] = ri[t + off];
      }
    }
    __syncthreads();
  }
  if (t == 0) out[row] = ri[0];
}

// ---------------------------------------------------------------------------
extern "C" void kernel_launch(void* const* d_in, const int* in_sizes, int n_in,
                              void* d_out, int out_size, void* d_ws, size_t ws_size,
                              hipStream_t stream) {
  const float* x = (const float*)d_in[0];    // [16, 512, 2048]
  const float* cen = (const float*)d_in[1];  // [512, 8192]
  int* out = (int*)d_out;                    // [32768] int32 labels

  const size_t XSZ = (size_t)32768 * 512;  // halfs
  const size_t CSZ = (size_t)8192 * 512;   // halfs
  const size_t OFF_CTH = XSZ * 2;
  const size_t OFF_CSQ = OFF_CTH + CSZ * 2;
  const size_t OFF_PK1 = OFF_CSQ + 8192 * 4;
  const size_t OFF_PV2 = OFF_PK1 + (size_t)64 * 32768 * 8;
  const size_t OFF_RB = OFF_PV2 + (size_t)64 * 32768 * 4;
  const size_t OFF_SLOT = OFF_RB + (size_t)32768 * 4;
  const size_t OFF_LIST = OFF_SLOT + (size_t)32768 * 8;
  const size_t OFF_LIST2 = OFF_LIST + (size_t)32768 * 4;
  const size_t OFF_CNT = OFF_LIST2 + (size_t)32768 * 4;
  const size_t NEED = OFF_CNT + 16;

  if (ws_size < NEED) {
    fallback_kernel<<<32768, 256, 0, stream>>>(x, cen, out);
    return;
  }

  char* ws = (char*)d_ws;
  _Float16* xh = (_Float16*)ws;
  _Float16* cth = (_Float16*)(ws + OFF_CTH);
  float* csq = (float*)(ws + OFF_CSQ);
  unsigned long long* pk1 = (unsigned long long*)(ws + OFF_PK1);
  unsigned int* pv2 = (unsigned int*)(ws + OFF_PV2);
  unsigned int* rowbest_m = (unsigned int*)(ws + OFF_RB);
  unsigned long long* slots = (unsigned long long*)(ws + OFF_SLOT);
  int* list = (int*)(ws + OFF_LIST);
  int* list2 = (int*)(ws + OFF_LIST2);
  unsigned int* cnts = (unsigned int*)(ws + OFF_CNT);  // [0]=cnt, [1]=cnt2

  tsplit_x<<<dim3(64, 16, 16), dim3(32, 8), 0, stream>>>(x, xh);
  tsplit_c<<<dim3(256, 16), dim3(32, 8), 0, stream>>>(cen, cth);
  csq_kernel<<<128, 256, 0, stream>>>(cen, csq);
  zero_cnts<<<1, 2, 0, stream>>>(cnts);
  gemm_top2<<<dim3(256, 64), 256, 0, stream>>>(xh, cth, csq, pk1, pv2);
  final_top2<<<128, 256, 0, stream>>>(pk1, pv2, out, rowbest_m, cnts, list);
  cand_refine<<<512, 256, 0, stream>>>(x, cen, csq, pk1, pv2, rowbest_m,
                                       cnts, list, cnts + 1, list2, slots, out);
  fullscan<<<256, 256, 0, stream>>>(x, cen, csq, cnts + 1, list2, slots);
  fixup2<<<4, 256, 0, stream>>>(cnts + 1, list2, slots, out);
}

// Round 8
// 770.542 us; speedup vs baseline: 1.3468x; 1.0838x over previous
//
#include <hip/hip_runtime.h>
#include <hip/hip_fp16.h>

typedef _Float16 half8 __attribute__((ext_vector_type(8)));
typedef float floatx4 __attribute__((ext_vector_type(4)));

#define TAU 0.25f
#define CMAX 128

__device__ inline unsigned long long score_key(float sc, int k) {
  unsigned uu = __float_as_uint(sc);
  uu ^= (unsigned)(((int)uu >> 31)) | 0x80000000u;  // monotone float->u32
  return ((unsigned long long)uu << 32) | (unsigned)k;
}

// ---------------------------------------------------------------------------
// Kernel 0a: transpose x [b=16, c=512, s=2048] f32 -> xh [row=b*2048+s][c] f16
// ---------------------------------------------------------------------------
__global__ void tsplit_x(const float* __restrict__ x, _Float16* __restrict__ xh) {
  __shared__ float tile[32][33];
  const int s0 = blockIdx.x * 32;
  const int c0 = blockIdx.y * 32;
  const int b = blockIdx.z;
  const int tx = threadIdx.x, ty = threadIdx.y;
  const float* src = x + ((size_t)b * 512 + c0) * 2048 + s0;
#pragma unroll
  for (int i = ty; i < 32; i += 8) tile[i][tx] = src[(size_t)i * 2048 + tx];
  __syncthreads();
#pragma unroll
  for (int j = ty; j < 32; j += 8) {
    const int row = b * 2048 + s0 + j;
    xh[(size_t)row * 512 + c0 + tx] = (_Float16)tile[tx][j];
  }
}

// ---------------------------------------------------------------------------
// Kernel 0b: transpose centroids [c=512, n=8192] f32 -> cth [n][c] f16
// ---------------------------------------------------------------------------
__global__ void tsplit_c(const float* __restrict__ c, _Float16* __restrict__ cth) {
  __shared__ float tile[32][33];
  const int n0 = blockIdx.x * 32;
  const int c0 = blockIdx.y * 32;
  const int tx = threadIdx.x, ty = threadIdx.y;
#pragma unroll
  for (int i = ty; i < 32; i += 8) tile[i][tx] = c[(size_t)(c0 + i) * 8192 + n0 + tx];
  __syncthreads();
#pragma unroll
  for (int j = ty; j < 32; j += 8)
    cth[(size_t)(n0 + j) * 512 + c0 + tx] = (_Float16)tile[tx][j];
}

// ---------------------------------------------------------------------------
// Kernel 0c: c_sq[n] = sum_c C[c][n]^2   (fp32, exact inputs)
// ---------------------------------------------------------------------------
__global__ void csq_kernel(const float* __restrict__ c, float* __restrict__ csq) {
  __shared__ float red[256];
  const int t = threadIdx.x;
  const int nl = t & 63;
  const int cs = t >> 6;  // 0..3
  const int n = blockIdx.x * 64 + nl;
  float acc = 0.f;
  for (int cc = cs; cc < 512; cc += 4) {
    float v = c[(size_t)cc * 8192 + n];
    acc = fmaf(v, v, acc);
  }
  red[t] = acc;
  __syncthreads();
  if (t < 64) csq[n] = red[t] + red[t + 64] + red[t + 128] + red[t + 192];
}

__global__ void zero_cnts(unsigned int* c) { c[threadIdx.x] = 0u; }  // cnt, cnt2

// ---------------------------------------------------------------------------
// Kernel 1: f16 GEMM + per-(row, nblock) top-2.  REGISTER-PREFETCH pipeline:
//   - tile kc+1 loaded global->VGPR (8x dwordx4/thread) DURING compute of kc;
//     regs written to LDS (ds_write_b128) at top of kc+1.  Loads are in
//     flight across the whole compute phase -> the barrier-drain stall that
//     bound the GLL structure (~60% idle) is gone even if the compiler
//     drains vmcnt at barriers.
//   - __launch_bounds__(256,3): +32 VGPR prefetch buffer -> 12 waves/CU.
//   - epilogue: R5-proven float shfl top-2, no i2 (needfull covers it).
// ---------------------------------------------------------------------------
__launch_bounds__(256, 3)
__global__ void gemm_top2(const _Float16* __restrict__ xh, const _Float16* __restrict__ cth,
                          const float* __restrict__ csq, float* __restrict__ pv1,
                          int* __restrict__ pi1, float* __restrict__ pv2) {
  __shared__ __align__(16) unsigned char smem[32768];
  __shared__ float ep_v1[128][2], ep_v2[128][2];
  __shared__ int ep_i1[128][2];

  const int t = threadIdx.x;
  const int m0 = blockIdx.x * 128;
  const int n0 = blockIdx.y * 128;

  // staging sources: chunk ch = p*256+t -> row = ch&127, kq = ch>>7 (half8 units)
  const half8* AP[4];
  const half8* BP[4];
#pragma unroll
  for (int p = 0; p < 4; ++p) {
    const int ch = p * 256 + t;
    const int row = ch & 127, kq = ch >> 7;
    AP[p] = (const half8*)(xh + (size_t)(m0 + row) * 512) + kq;
    BP[p] = (const half8*)(cth + (size_t)(n0 + row) * 512) + kq;
  }

  const int l = t & 63;
  const int w = t >> 6;
  const int wm = w >> 1, wn = w & 1;
  const int l15 = l & 15, lq = l >> 4;
  const int aBase = wm * 64 + l15;
  const int bBase = 1024 + wn * 64 + l15;

  floatx4 acc[4][4] = {};
  const half8* S = (const half8*)smem;
  half8* SW = (half8*)smem;

  half8 pfA[4], pfB[4];
#pragma unroll
  for (int p = 0; p < 4; ++p) {
    pfA[p] = AP[p][0];
    pfB[p] = BP[p][0];
  }

  for (int kc = 0; kc < 8; ++kc) {
    __syncthreads();  // previous iteration's ds_reads complete (lgkm only)
#pragma unroll
    for (int p = 0; p < 4; ++p) {
      SW[p * 256 + t] = pfA[p];
      SW[1024 + p * 256 + t] = pfB[p];
    }
    if (kc < 7) {
      const int o = (kc + 1) * 8;
#pragma unroll
      for (int p = 0; p < 4; ++p) {
        pfA[p] = AP[p][o];
        pfB[p] = BP[p][o];
      }
    }
    __syncthreads();  // LDS writes visible
#pragma unroll
    for (int ks = 0; ks < 2; ++ks) {
      const int ko = (ks * 4 + lq) * 128;
      half8 a[4], b[4];
#pragma unroll
      for (int f = 0; f < 4; ++f) {
        a[f] = S[ko + aBase + f * 16];
        b[f] = S[ko + bBase + f * 16];
      }
#pragma unroll
      for (int mf = 0; mf < 4; ++mf)
#pragma unroll
        for (int nf = 0; nf < 4; ++nf)
          acc[mf][nf] = __builtin_amdgcn_mfma_f32_16x16x32_f16(a[mf], b[nf], acc[mf][nf], 0, 0, 0);
    }
  }

  // ---- epilogue: top-2 over this block's 128 cols (float shfl, R5-proven)
  float cs[4];
#pragma unroll
  for (int nf = 0; nf < 4; ++nf) cs[nf] = csq[n0 + wn * 64 + nf * 16 + l15];

#pragma unroll
  for (int mf = 0; mf < 4; ++mf) {
#pragma unroll
    for (int reg = 0; reg < 4; ++reg) {
      float v1 = INFINITY, v2 = INFINITY;
      int i1 = 0;
#pragma unroll
      for (int nf = 0; nf < 4; ++nf) {
        float sv = fmaf(-2.f, acc[mf][nf][reg], cs[nf]);
        int si = n0 + wn * 64 + nf * 16 + l15;
        if (sv < v1) { v2 = v1; v1 = sv; i1 = si; }
        else if (sv < v2) { v2 = sv; }
      }
#pragma unroll
      for (int off = 8; off >= 1; off >>= 1) {
        float w1 = __shfl_xor(v1, off, 64);
        int j1 = __shfl_xor(i1, off, 64);
        float w2 = __shfl_xor(v2, off, 64);
        if (w1 < v1 || (w1 == v1 && j1 < i1)) {
          v2 = fminf(v1, w2);
          v1 = w1; i1 = j1;
        } else {
          v2 = fminf(v2, w1);
        }
      }
      if (l15 == 0) {
        int rl = wm * 64 + mf * 16 + lq * 4 + reg;
        ep_v1[rl][wn] = v1;
        ep_i1[rl][wn] = i1;
        ep_v2[rl][wn] = v2;
      }
    }
  }
  __syncthreads();
  if (t < 128) {
    float v1 = ep_v1[t][0], v2 = ep_v2[t][0];
    int i1 = ep_i1[t][0];
    float w1 = ep_v1[t][1], w2 = ep_v2[t][1];
    int j1 = ep_i1[t][1];
    if (w1 < v1 || (w1 == v1 && j1 < i1)) {
      v2 = fminf(v1, w2);
      v1 = w1; i1 = j1;
    } else {
      v2 = fminf(v2, w1);
    }
    const size_t o = (size_t)blockIdx.y * 32768 + m0 + t;
    pv1[o] = v1;
    pi1[o] = i1;
    pv2[o] = v2;
  }
}

// ---------------------------------------------------------------------------
// Kernel 2: merge 64 nblock top-2s; write labels + rowbest; flag small margins.
// ---------------------------------------------------------------------------
__global__ void final_top2(const float* __restrict__ pv1, const int* __restrict__ pi1,
                           const float* __restrict__ pv2, int* __restrict__ out,
                           float* __restrict__ rowbest, unsigned int* __restrict__ cnt,
                           int* __restrict__ list) {
  const int row = blockIdx.x * 256 + threadIdx.x;
  float v1 = INFINITY, v2 = INFINITY;
  int i1 = 0;
  for (int nb = 0; nb < 64; ++nb) {
    const size_t o = (size_t)nb * 32768 + row;
    float w1 = pv1[o], w2 = pv2[o];
    int j1 = pi1[o];
    if (w1 < v1 || (w1 == v1 && j1 < i1)) {
      v2 = fminf(v1, w2);
      v1 = w1; i1 = j1;
    } else {
      v2 = fminf(v2, w1);
    }
  }
  out[row] = i1;
  rowbest[row] = v1;
  if (v2 - v1 < TAU) {
    unsigned int pos = atomicAdd(cnt, 1u);
    list[pos] = row;
  }
}

// ---------------------------------------------------------------------------
// Kernel 3: candidate-set exact rescore for flagged rows.
//   Candidates = per-nblock winners with approx score < v1g + TAU.  Any
//   nblock whose v2 < thr may hide a 3rd candidate -> full scan that row.
// ---------------------------------------------------------------------------
__global__ void cand_refine(const float* __restrict__ x, const float* __restrict__ cen,
                            const float* __restrict__ csq, const float* __restrict__ pv1,
                            const int* __restrict__ pi1, const float* __restrict__ pv2,
                            const float* __restrict__ rowbest,
                            const unsigned int* __restrict__ cnt, const int* __restrict__ list,
                            unsigned int* __restrict__ cnt2, int* __restrict__ list2,
                            unsigned long long* __restrict__ slots, int* __restrict__ out) {
  __shared__ float xs[512];
  __shared__ int cand[CMAX];
  __shared__ int ccnt_s, needfull_s;
  __shared__ unsigned long long wbest[4];
  const int t = threadIdx.x;
  const int lane = t & 63, wid = t >> 6;
  const int n = (int)*cnt;
  for (int u = blockIdx.x; u < n; u += gridDim.x) {
    __syncthreads();  // protect previous iteration's xs/cand readers
    const int row = list[u];
    const int b = row >> 11, s = row & 2047;
    if (t == 0) { ccnt_s = 0; needfull_s = 0; }
    __syncthreads();
    xs[t] = x[((size_t)(b * 512 + t)) * 2048 + s];
    xs[t + 256] = x[((size_t)(b * 512 + t + 256)) * 2048 + s];
    const float thr = rowbest[row] + TAU;
    if (t < 64) {
      const size_t o = (size_t)t * 32768 + row;
      float w1 = pv1[o];
      if (w1 < thr) {
        int p = atomicAdd(&ccnt_s, 1);
        if (p < CMAX) cand[p] = pi1[o];
        if (pv2[o] < thr) needfull_s = 1;
      }
    }
    __syncthreads();
    int ccnt = ccnt_s < CMAX ? ccnt_s : CMAX;
    unsigned long long best = ~0ULL;
    for (int ci = wid; ci < ccnt; ci += 4) {
      const int k = cand[ci];
      float p0 = 0.f, p1 = 0.f;
#pragma unroll
      for (int j = 0; j < 4; ++j)
        p0 = fmaf(xs[lane + 64 * j], cen[(size_t)(lane + 64 * j) * 8192 + k], p0);
#pragma unroll
      for (int j = 4; j < 8; ++j)
        p1 = fmaf(xs[lane + 64 * j], cen[(size_t)(lane + 64 * j) * 8192 + k], p1);
      float d = p0 + p1;
#pragma unroll
      for (int off = 32; off >= 1; off >>= 1) d += __shfl_xor(d, off, 64);
      unsigned long long key = score_key(fmaf(-2.f, d, csq[k]), k);
      if (key < best) best = key;
    }
    if (lane == 0) wbest[wid] = best;
    __syncthreads();
    if (t == 0) {
      unsigned long long m = wbest[0];
#pragma unroll
      for (int w2 = 1; w2 < 4; ++w2)
        if (wbest[w2] < m) m = wbest[w2];
      out[row] = (int)(unsigned)(m & 0xFFFFFFFFULL);
      if (needfull_s) {
        slots[row] = ~0ULL;
        unsigned int pos = atomicAdd(cnt2, 1u);
        list2[pos] = row;
      }
    }
  }
}

// ---------------------------------------------------------------------------
// Kernel 4: full 8192-scan for the rare rows needing it.
// ---------------------------------------------------------------------------
__global__ void fullscan(const float* __restrict__ x, const float* __restrict__ cen,
                         const float* __restrict__ csq, const unsigned int* __restrict__ cnt2,
                         const int* __restrict__ list2, unsigned long long* __restrict__ slots) {
  __shared__ float xs[512];
  __shared__ unsigned long long red[256];
  const int t = threadIdx.x;
  const int n2 = (int)*cnt2;
  const int units = n2 * 16;
  for (int u = blockIdx.x; u < units; u += gridDim.x) {
    __syncthreads();
    const int row = list2[u >> 4];
    const int sl = u & 15;
    const int b = row >> 11, s = row & 2047;
    xs[t] = x[((size_t)(b * 512 + t)) * 2048 + s];
    xs[t + 256] = x[((size_t)(b * 512 + t + 256)) * 2048 + s];
    __syncthreads();
    const int k0 = sl * 512 + t;
    float tot0 = 0.f, tot1 = 0.f;
#pragma unroll
    for (int ch = 0; ch < 4; ++ch) {
      float a0 = 0.f, a1 = 0.f;
      for (int c = ch * 128; c < ch * 128 + 128; ++c) {
        float xv = xs[c];
        a0 = fmaf(xv, cen[(size_t)c * 8192 + k0], a0);
        a1 = fmaf(xv, cen[(size_t)c * 8192 + k0 + 256], a1);
      }
      tot0 += a0;
      tot1 += a1;
    }
    unsigned long long k1 = score_key(fmaf(-2.f, tot0, csq[k0]), k0);
    unsigned long long k2 = score_key(fmaf(-2.f, tot1, csq[k0 + 256]), k0 + 256);
    red[t] = k1 < k2 ? k1 : k2;
    __syncthreads();
    for (int off = 128; off >= 1; off >>= 1) {
      if (t < off && red[t + off] < red[t]) red[t] = red[t + off];
      __syncthreads();
    }
    if (t == 0) atomicMin(&slots[row], red[0]);
  }
}

// ---------------------------------------------------------------------------
// Kernel 5: fold fullscan results into labels.
// ---------------------------------------------------------------------------
__global__ void fixup2(const unsigned int* __restrict__ cnt2, const int* __restrict__ list2,
                       const unsigned long long* __restrict__ slots, int* __restrict__ out) {
  const int n2 = (int)*cnt2;
  for (int i = blockIdx.x * blockDim.x + threadIdx.x; i < n2; i += blockDim.x * gridDim.x) {
    const int row = list2[i];
    out[row] = (int)(unsigned)(slots[row] & 0xFFFFFFFFULL);
  }
}

// ---------------------------------------------------------------------------
// Fallback (only if ws too small): exact distances, slow but correct.
// ---------------------------------------------------------------------------
__global__ void fallback_kernel(const float* __restrict__ x, const float* __restrict__ cen,
                                int* __restrict__ out) {
  __shared__ float xrow[512];
  __shared__ float rv[256];
  __shared__ int ri[256];
  const int row = blockIdx.x;
  const int b = row >> 11, s = row & 2047;
  const int t = threadIdx.x;
  for (int c = t; c < 512; c += 256) xrow[c] = x[((size_t)b * 512 + c) * 2048 + s];
  __syncthreads();
  float bv = INFINITY;
  int bi = 0;
  for (int k = t; k < 8192; k += 256) {
    float d = 0.f;
    for (int c = 0; c < 512; ++c) {
      float diff = xrow[c] - cen[(size_t)c * 8192 + k];
      d = fmaf(diff, diff, d);
    }
    if (d < bv) { bv = d; bi = k; }
  }
  rv[t] = bv;
  ri[t] = bi;
  __syncthreads();
  for (int off = 128; off > 0; off >>= 1) {
    if (t < off) {
      if (rv[t + off] < rv[t] || (rv[t + off] == rv[t] && ri[t + off] < ri[t])) {
        rv[t] = rv[t + off];
        ri[t] = ri[t + off];
      }
    }
    __syncthreads();
  }
  if (t == 0) out[row] = ri[0];
}

// ---------------------------------------------------------------------------
extern "C" void kernel_launch(void* const* d_in, const int* in_sizes, int n_in,
                              void* d_out, int out_size, void* d_ws, size_t ws_size,
                              hipStream_t stream) {
  const float* x = (const float*)d_in[0];    // [16, 512, 2048]
  const float* cen = (const float*)d_in[1];  // [512, 8192]
  int* out = (int*)d_out;                    // [32768] int32 labels

  const size_t XSZ = (size_t)32768 * 512;  // halfs
  const size_t CSZ = (size_t)8192 * 512;   // halfs
  const size_t OFF_CTH = XSZ * 2;
  const size_t OFF_CSQ = OFF_CTH + CSZ * 2;
  const size_t OFF_PV1 = OFF_CSQ + 8192 * 4;
  const size_t OFF_PI1 = OFF_PV1 + (size_t)64 * 32768 * 4;
  const size_t OFF_PV2 = OFF_PI1 + (size_t)64 * 32768 * 4;
  const size_t OFF_RB = OFF_PV2 + (size_t)64 * 32768 * 4;
  const size_t OFF_SLOT = OFF_RB + (size_t)32768 * 4;
  const size_t OFF_LIST = OFF_SLOT + (size_t)32768 * 8;
  const size_t OFF_LIST2 = OFF_LIST + (size_t)32768 * 4;
  const size_t OFF_CNT = OFF_LIST2 + (size_t)32768 * 4;
  const size_t NEED = OFF_CNT + 16;

  if (ws_size < NEED) {
    fallback_kernel<<<32768, 256, 0, stream>>>(x, cen, out);
    return;
  }

  char* ws = (char*)d_ws;
  _Float16* xh = (_Float16*)ws;
  _Float16* cth = (_Float16*)(ws + OFF_CTH);
  float* csq = (float*)(ws + OFF_CSQ);
  float* pv1 = (float*)(ws + OFF_PV1);
  int* pi1 = (int*)(ws + OFF_PI1);
  float* pv2 = (float*)(ws + OFF_PV2);
  float* rowbest = (float*)(ws + OFF_RB);
  unsigned long long* slots = (unsigned long long*)(ws + OFF_SLOT);
  int* list = (int*)(ws + OFF_LIST);
  int* list2 = (int*)(ws + OFF_LIST2);
  unsigned int* cnts = (unsigned int*)(ws + OFF_CNT);  // [0]=cnt, [1]=cnt2

  tsplit_x<<<dim3(64, 16, 16), dim3(32, 8), 0, stream>>>(x, xh);
  tsplit_c<<<dim3(256, 16), dim3(32, 8), 0, stream>>>(cen, cth);
  csq_kernel<<<128, 256, 0, stream>>>(cen, csq);
  zero_cnts<<<1, 2, 0, stream>>>(cnts);
  gemm_top2<<<dim3(256, 64), 256, 0, stream>>>(xh, cth, csq, pv1, pi1, pv2);
  final_top2<<<128, 256, 0, stream>>>(pv1, pi1, pv2, out, rowbest, cnts, list);
  cand_refine<<<512, 256, 0, stream>>>(x, cen, csq, pv1, pi1, pv2, rowbest,
                                       cnts, list, cnts + 1, list2, slots, out);
  fullscan<<<256, 256, 0, stream>>>(x, cen, csq, cnts + 1, list2, slots);
  fixup2<<<4, 256, 0, stream>>>(cnts + 1, list2, slots, out);
}

// Round 9
// 735.706 us; speedup vs baseline: 1.4106x; 1.0474x over previous
//
#include <hip/hip_runtime.h>
#include <hip/hip_fp16.h>

typedef _Float16 half8 __attribute__((ext_vector_type(8)));
typedef float floatx4 __attribute__((ext_vector_type(4)));

#define TAU 0.25f
#define CMAX 128

__device__ inline unsigned long long score_key(float sc, int k) {
  unsigned uu = __float_as_uint(sc);
  uu ^= (unsigned)(((int)uu >> 31)) | 0x80000000u;  // monotone float->u32
  return ((unsigned long long)uu << 32) | (unsigned)k;
}

// ---------------------------------------------------------------------------
// Kernel 0a: transpose x [b=16, c=512, s=2048] f32 -> xh [row=b*2048+s][c] f16
// ---------------------------------------------------------------------------
__global__ void tsplit_x(const float* __restrict__ x, _Float16* __restrict__ xh) {
  __shared__ float tile[32][33];
  const int s0 = blockIdx.x * 32;
  const int c0 = blockIdx.y * 32;
  const int b = blockIdx.z;
  const int tx = threadIdx.x, ty = threadIdx.y;
  const float* src = x + ((size_t)b * 512 + c0) * 2048 + s0;
#pragma unroll
  for (int i = ty; i < 32; i += 8) tile[i][tx] = src[(size_t)i * 2048 + tx];
  __syncthreads();
#pragma unroll
  for (int j = ty; j < 32; j += 8) {
    const int row = b * 2048 + s0 + j;
    xh[(size_t)row * 512 + c0 + tx] = (_Float16)tile[tx][j];
  }
}

// ---------------------------------------------------------------------------
// Kernel 0b: transpose centroids [c=512, n=8192] f32 -> cth [n][c] f16
// ---------------------------------------------------------------------------
__global__ void tsplit_c(const float* __restrict__ c, _Float16* __restrict__ cth) {
  __shared__ float tile[32][33];
  const int n0 = blockIdx.x * 32;
  const int c0 = blockIdx.y * 32;
  const int tx = threadIdx.x, ty = threadIdx.y;
#pragma unroll
  for (int i = ty; i < 32; i += 8) tile[i][tx] = c[(size_t)(c0 + i) * 8192 + n0 + tx];
  __syncthreads();
#pragma unroll
  for (int j = ty; j < 32; j += 8)
    cth[(size_t)(n0 + j) * 512 + c0 + tx] = (_Float16)tile[tx][j];
}

// ---------------------------------------------------------------------------
// Kernel 0c: c_sq[n] = sum_c C[c][n]^2 (fp32, exact inputs) + zero counters.
// ---------------------------------------------------------------------------
__global__ void csq_kernel(const float* __restrict__ c, float* __restrict__ csq,
                           unsigned int* __restrict__ cnts) {
  __shared__ float red[256];
  const int t = threadIdx.x;
  if (blockIdx.x == 0 && t < 2) cnts[t] = 0u;
  const int nl = t & 63;
  const int cs = t >> 6;  // 0..3
  const int n = blockIdx.x * 64 + nl;
  float acc = 0.f;
  for (int cc = cs; cc < 512; cc += 4) {
    float v = c[(size_t)cc * 8192 + n];
    acc = fmaf(v, v, acc);
  }
  red[t] = acc;
  __syncthreads();
  if (t < 64) csq[n] = red[t] + red[t + 64] + red[t + 128] + red[t + 192];
}

// ---------------------------------------------------------------------------
// Kernel 1: f16 GEMM + per-(row, nblock) top-2.
//   BK=32, LDS double-buffered 2x16 KiB -> ONE barrier per kc (16 total).
//   Register prefetch (16 VGPRs): tile kc+2 loaded global->VGPR during kc
//   (reg loads float across barriers — thread-private), regs->LDS ds_write
//   into buf^1 while buf is being read.  Target: VGPR+AGPR <= 128 ->
//   4 waves/SIMD (16 waves/CU) vs R8's 3.
// ---------------------------------------------------------------------------
__launch_bounds__(256, 4)
__global__ void gemm_top2(const _Float16* __restrict__ xh, const _Float16* __restrict__ cth,
                          const float* __restrict__ csq, float* __restrict__ pv1,
                          int* __restrict__ pi1, float* __restrict__ pv2) {
  __shared__ __align__(16) unsigned char smem[32768];  // 2 bufs x (A 8K + B 8K)
  __shared__ float ep_v1[128][2], ep_v2[128][2];
  __shared__ int ep_i1[128][2];

  const int t = threadIdx.x;
  const int m0 = blockIdx.x * 128;
  const int n0 = blockIdx.y * 128;

  // staging: per kc each thread owns 2 A-chunks + 2 B-chunks (16B each).
  // chunk ch in {t, t+256}: row = t&127, kq = (ch>>7) in {t>>7, 2+(t>>7)}.
  const int srow = t & 127;
  const int kq1 = t >> 7, kq2 = 2 + (t >> 7);
  const half8* APb = (const half8*)(xh + (size_t)(m0 + srow) * 512);
  const half8* BPb = (const half8*)(cth + (size_t)(n0 + srow) * 512);

  const int l = t & 63;
  const int w = t >> 6;
  const int wm = w >> 1, wn = w & 1;
  const int l15 = l & 15, lq = l >> 4;
  const int aBase = lq * 128 + wm * 64 + l15;        // + mf*16  (half8 idx)
  const int bBase = 512 + lq * 128 + wn * 64 + l15;  // + nf*16

  floatx4 acc[4][4] = {};
  const half8* S = (const half8*)smem;
  half8* SW = (half8*)smem;

  half8 pfA0, pfA1, pfB0, pfB1;
  // prologue: load kc=0, write to buf0, load kc=1
  pfA0 = APb[kq1]; pfA1 = APb[kq2];
  pfB0 = BPb[kq1]; pfB1 = BPb[kq2];
  SW[t] = pfA0; SW[256 + t] = pfA1;
  SW[512 + t] = pfB0; SW[768 + t] = pfB1;
  pfA0 = APb[4 + kq1]; pfA1 = APb[4 + kq2];
  pfB0 = BPb[4 + kq1]; pfB1 = BPb[4 + kq2];

  for (int kc = 0; kc < 16; ++kc) {
    __syncthreads();  // buf(kc&1) writes visible; buf^1's old readers done
    const int bo = (kc & 1) * 1024;
    half8 a[4], b[4];
#pragma unroll
    for (int f = 0; f < 4; ++f) {
      a[f] = S[bo + aBase + f * 16];
      b[f] = S[bo + bBase + f * 16];
    }
#pragma unroll
    for (int mf = 0; mf < 4; ++mf)
#pragma unroll
      for (int nf = 0; nf < 4; ++nf)
        acc[mf][nf] = __builtin_amdgcn_mfma_f32_16x16x32_f16(a[mf], b[nf], acc[mf][nf], 0, 0, 0);
    if (kc < 15) {
      const int wo = ((kc + 1) & 1) * 1024;
      SW[wo + t] = pfA0; SW[wo + 256 + t] = pfA1;
      SW[wo + 512 + t] = pfB0; SW[wo + 768 + t] = pfB1;
      if (kc < 14) {
        const int o = (kc + 2) * 4;
        pfA0 = APb[o + kq1]; pfA1 = APb[o + kq2];
        pfB0 = BPb[o + kq1]; pfB1 = BPb[o + kq2];
      }
    }
  }

  // ---- epilogue: top-2 over this block's 128 cols (float shfl, R5-proven)
  float cs[4];
#pragma unroll
  for (int nf = 0; nf < 4; ++nf) cs[nf] = csq[n0 + wn * 64 + nf * 16 + l15];

#pragma unroll
  for (int mf = 0; mf < 4; ++mf) {
#pragma unroll
    for (int reg = 0; reg < 4; ++reg) {
      float v1 = INFINITY, v2 = INFINITY;
      int i1 = 0;
#pragma unroll
      for (int nf = 0; nf < 4; ++nf) {
        float sv = fmaf(-2.f, acc[mf][nf][reg], cs[nf]);
        int si = n0 + wn * 64 + nf * 16 + l15;
        if (sv < v1) { v2 = v1; v1 = sv; i1 = si; }
        else if (sv < v2) { v2 = sv; }
      }
#pragma unroll
      for (int off = 8; off >= 1; off >>= 1) {
        float w1 = __shfl_xor(v1, off, 64);
        int j1 = __shfl_xor(i1, off, 64);
        float w2 = __shfl_xor(v2, off, 64);
        if (w1 < v1 || (w1 == v1 && j1 < i1)) {
          v2 = fminf(v1, w2);
          v1 = w1; i1 = j1;
        } else {
          v2 = fminf(v2, w1);
        }
      }
      if (l15 == 0) {
        int rl = wm * 64 + mf * 16 + lq * 4 + reg;
        ep_v1[rl][wn] = v1;
        ep_i1[rl][wn] = i1;
        ep_v2[rl][wn] = v2;
      }
    }
  }
  __syncthreads();
  if (t < 128) {
    float v1 = ep_v1[t][0], v2 = ep_v2[t][0];
    int i1 = ep_i1[t][0];
    float w1 = ep_v1[t][1], w2 = ep_v2[t][1];
    int j1 = ep_i1[t][1];
    if (w1 < v1 || (w1 == v1 && j1 < i1)) {
      v2 = fminf(v1, w2);
      v1 = w1; i1 = j1;
    } else {
      v2 = fminf(v2, w1);
    }
    const size_t o = (size_t)blockIdx.y * 32768 + m0 + t;
    pv1[o] = v1;
    pi1[o] = i1;
    pv2[o] = v2;
  }
}

// ---------------------------------------------------------------------------
// Kernel 2: merge 64 nblock top-2s; write labels + rowbest; flag small margins.
// ---------------------------------------------------------------------------
__global__ void final_top2(const float* __restrict__ pv1, const int* __restrict__ pi1,
                           const float* __restrict__ pv2, int* __restrict__ out,
                           float* __restrict__ rowbest, unsigned int* __restrict__ cnt,
                           int* __restrict__ list) {
  const int row = blockIdx.x * 256 + threadIdx.x;
  float v1 = INFINITY, v2 = INFINITY;
  int i1 = 0;
  for (int nb = 0; nb < 64; ++nb) {
    const size_t o = (size_t)nb * 32768 + row;
    float w1 = pv1[o], w2 = pv2[o];
    int j1 = pi1[o];
    if (w1 < v1 || (w1 == v1 && j1 < i1)) {
      v2 = fminf(v1, w2);
      v1 = w1; i1 = j1;
    } else {
      v2 = fminf(v2, w1);
    }
  }
  out[row] = i1;
  rowbest[row] = v1;
  if (v2 - v1 < TAU) {
    unsigned int pos = atomicAdd(cnt, 1u);
    list[pos] = row;
  }
}

// ---------------------------------------------------------------------------
// Kernel 3: candidate-set exact rescore for flagged rows.
//   Candidates = per-nblock winners with approx score < v1g + TAU.  Any
//   nblock whose v2 < thr may hide a 3rd candidate -> full scan that row.
// ---------------------------------------------------------------------------
__global__ void cand_refine(const float* __restrict__ x, const float* __restrict__ cen,
                            const float* __restrict__ csq, const float* __restrict__ pv1,
                            const int* __restrict__ pi1, const float* __restrict__ pv2,
                            const float* __restrict__ rowbest,
                            const unsigned int* __restrict__ cnt, const int* __restrict__ list,
                            unsigned int* __restrict__ cnt2, int* __restrict__ list2,
                            unsigned long long* __restrict__ slots, int* __restrict__ out) {
  __shared__ float xs[512];
  __shared__ int cand[CMAX];
  __shared__ int ccnt_s, needfull_s;
  __shared__ unsigned long long wbest[4];
  const int t = threadIdx.x;
  const int lane = t & 63, wid = t >> 6;
  const int n = (int)*cnt;
  for (int u = blockIdx.x; u < n; u += gridDim.x) {
    __syncthreads();  // protect previous iteration's xs/cand readers
    const int row = list[u];
    const int b = row >> 11, s = row & 2047;
    if (t == 0) { ccnt_s = 0; needfull_s = 0; }
    __syncthreads();
    xs[t] = x[((size_t)(b * 512 + t)) * 2048 + s];
    xs[t + 256] = x[((size_t)(b * 512 + t + 256)) * 2048 + s];
    const float thr = rowbest[row] + TAU;
    if (t < 64) {
      const size_t o = (size_t)t * 32768 + row;
      float w1 = pv1[o];
      if (w1 < thr) {
        int p = atomicAdd(&ccnt_s, 1);
        if (p < CMAX) cand[p] = pi1[o];
        if (pv2[o] < thr) needfull_s = 1;
      }
    }
    __syncthreads();
    int ccnt = ccnt_s < CMAX ? ccnt_s : CMAX;
    unsigned long long best = ~0ULL;
    for (int ci = wid; ci < ccnt; ci += 4) {
      const int k = cand[ci];
      float p0 = 0.f, p1 = 0.f;
#pragma unroll
      for (int j = 0; j < 4; ++j)
        p0 = fmaf(xs[lane + 64 * j], cen[(size_t)(lane + 64 * j) * 8192 + k], p0);
#pragma unroll
      for (int j = 4; j < 8; ++j)
        p1 = fmaf(xs[lane + 64 * j], cen[(size_t)(lane + 64 * j) * 8192 + k], p1);
      float d = p0 + p1;
#pragma unroll
      for (int off = 32; off >= 1; off >>= 1) d += __shfl_xor(d, off, 64);
      unsigned long long key = score_key(fmaf(-2.f, d, csq[k]), k);
      if (key < best) best = key;
    }
    if (lane == 0) wbest[wid] = best;
    __syncthreads();
    if (t == 0) {
      unsigned long long m = wbest[0];
#pragma unroll
      for (int w2 = 1; w2 < 4; ++w2)
        if (wbest[w2] < m) m = wbest[w2];
      out[row] = (int)(unsigned)(m & 0xFFFFFFFFULL);
      if (needfull_s) {
        slots[row] = ~0ULL;
        unsigned int pos = atomicAdd(cnt2, 1u);
        list2[pos] = row;
      }
    }
  }
}

// ---------------------------------------------------------------------------
// Kernel 4: full 8192-scan for the rare rows needing it.
// ---------------------------------------------------------------------------
__global__ void fullscan(const float* __restrict__ x, const float* __restrict__ cen,
                         const float* __restrict__ csq, const unsigned int* __restrict__ cnt2,
                         const int* __restrict__ list2, unsigned long long* __restrict__ slots) {
  __shared__ float xs[512];
  __shared__ unsigned long long red[256];
  const int t = threadIdx.x;
  const int n2 = (int)*cnt2;
  const int units = n2 * 16;
  for (int u = blockIdx.x; u < units; u += gridDim.x) {
    __syncthreads();
    const int row = list2[u >> 4];
    const int sl = u & 15;
    const int b = row >> 11, s = row & 2047;
    xs[t] = x[((size_t)(b * 512 + t)) * 2048 + s];
    xs[t + 256] = x[((size_t)(b * 512 + t + 256)) * 2048 + s];
    __syncthreads();
    const int k0 = sl * 512 + t;
    float tot0 = 0.f, tot1 = 0.f;
#pragma unroll
    for (int ch = 0; ch < 4; ++ch) {
      float a0 = 0.f, a1 = 0.f;
      for (int c = ch * 128; c < ch * 128 + 128; ++c) {
        float xv = xs[c];
        a0 = fmaf(xv, cen[(size_t)c * 8192 + k0], a0);
        a1 = fmaf(xv, cen[(size_t)c * 8192 + k0 + 256], a1);
      }
      tot0 += a0;
      tot1 += a1;
    }
    unsigned long long k1 = score_key(fmaf(-2.f, tot0, csq[k0]), k0);
    unsigned long long k2 = score_key(fmaf(-2.f, tot1, csq[k0 + 256]), k0 + 256);
    red[t] = k1 < k2 ? k1 : k2;
    __syncthreads();
    for (int off = 128; off >= 1; off >>= 1) {
      if (t < off && red[t + off] < red[t]) red[t] = red[t + off];
      __syncthreads();
    }
    if (t == 0) atomicMin(&slots[row], red[0]);
  }
}

// ---------------------------------------------------------------------------
// Kernel 5: fold fullscan results into labels.
// ---------------------------------------------------------------------------
__global__ void fixup2(const unsigned int* __restrict__ cnt2, const int* __restrict__ list2,
                       const unsigned long long* __restrict__ slots, int* __restrict__ out) {
  const int n2 = (int)*cnt2;
  for (int i = blockIdx.x * blockDim.x + threadIdx.x; i < n2; i += blockDim.x * gridDim.x) {
    const int row = list2[i];
    out[row] = (int)(unsigned)(slots[row] & 0xFFFFFFFFULL);
  }
}

// ---------------------------------------------------------------------------
// Fallback (only if ws too small): exact distances, slow but correct.
// ---------------------------------------------------------------------------
__global__ void fallback_kernel(const float* __restrict__ x, const float* __restrict__ cen,
                                int* __restrict__ out) {
  __shared__ float xrow[512];
  __shared__ float rv[256];
  __shared__ int ri[256];
  const int row = blockIdx.x;
  const int b = row >> 11, s = row & 2047;
  const int t = threadIdx.x;
  for (int c = t; c < 512; c += 256) xrow[c] = x[((size_t)b * 512 + c) * 2048 + s];
  __syncthreads();
  float bv = INFINITY;
  int bi = 0;
  for (int k = t; k < 8192; k += 256) {
    float d = 0.f;
    for (int c = 0; c < 512; ++c) {
      float diff = xrow[c] - cen[(size_t)c * 8192 + k];
      d = fmaf(diff, diff, d);
    }
    if (d < bv) { bv = d; bi = k; }
  }
  rv[t] = bv;
  ri[t] = bi;
  __syncthreads();
  for (int off = 128; off > 0; off >>= 1) {
    if (t < off) {
      if (rv[t + off] < rv[t] || (rv[t + off] == rv[t] && ri[t + off] < ri[t])) {
        rv[t] = rv[t + off];
        ri[t] = ri[t + off];
      }
    }
    __syncthreads();
  }
  if (t == 0) out[row] = ri[0];
}

// ---------------------------------------------------------------------------
extern "C" void kernel_launch(void* const* d_in, const int* in_sizes, int n_in,
                              void* d_out, int out_size, void* d_ws, size_t ws_size,
                              hipStream_t stream) {
  const float* x = (const float*)d_in[0];    // [16, 512, 2048]
  const float* cen = (const float*)d_in[1];  // [512, 8192]
  int* out = (int*)d_out;                    // [32768] int32 labels

  const size_t XSZ = (size_t)32768 * 512;  // halfs
  const size_t CSZ = (size_t)8192 * 512;   // halfs
  const size_t OFF_CTH = XSZ * 2;
  const size_t OFF_CSQ = OFF_CTH + CSZ * 2;
  const size_t OFF_PV1 = OFF_CSQ + 8192 * 4;
  const size_t OFF_PI1 = OFF_PV1 + (size_t)64 * 32768 * 4;
  const size_t OFF_PV2 = OFF_PI1 + (size_t)64 * 32768 * 4;
  const size_t OFF_RB = OFF_PV2 + (size_t)64 * 32768 * 4;
  const size_t OFF_SLOT = OFF_RB + (size_t)32768 * 4;
  const size_t OFF_LIST = OFF_SLOT + (size_t)32768 * 8;
  const size_t OFF_LIST2 = OFF_LIST + (size_t)32768 * 4;
  const size_t OFF_CNT = OFF_LIST2 + (size_t)32768 * 4;
  const size_t NEED = OFF_CNT + 16;

  if (ws_size < NEED) {
    fallback_kernel<<<32768, 256, 0, stream>>>(x, cen, out);
    return;
  }

  char* ws = (char*)d_ws;
  _Float16* xh = (_Float16*)ws;
  _Float16* cth = (_Float16*)(ws + OFF_CTH);
  float* csq = (float*)(ws + OFF_CSQ);
  float* pv1 = (float*)(ws + OFF_PV1);
  int* pi1 = (int*)(ws + OFF_PI1);
  float* pv2 = (float*)(ws + OFF_PV2);
  float* rowbest = (float*)(ws + OFF_RB);
  unsigned long long* slots = (unsigned long long*)(ws + OFF_SLOT);
  int* list = (int*)(ws + OFF_LIST);
  int* list2 = (int*)(ws + OFF_LIST2);
  unsigned int* cnts = (unsigned int*)(ws + OFF_CNT);  // [0]=cnt, [1]=cnt2

  tsplit_x<<<dim3(64, 16, 16), dim3(32, 8), 0, stream>>>(x, xh);
  tsplit_c<<<dim3(256, 16), dim3(32, 8), 0, stream>>>(cen, cth);
  csq_kernel<<<128, 256, 0, stream>>>(cen, csq, cnts);
  gemm_top2<<<dim3(256, 64), 256, 0, stream>>>(xh, cth, csq, pv1, pi1, pv2);
  final_top2<<<128, 256, 0, stream>>>(pv1, pi1, pv2, out, rowbest, cnts, list);
  cand_refine<<<512, 256, 0, stream>>>(x, cen, csq, pv1, pi1, pv2, rowbest,
                                       cnts, list, cnts + 1, list2, slots, out);
  fullscan<<<256, 256, 0, stream>>>(x, cen, csq, cnts + 1, list2, slots);
  fixup2<<<4, 256, 0, stream>>>(cnts + 1, list2, slots, out);
}